// Round 2
// baseline (2952.651 us; speedup 1.0000x reference)
//
#include <hip/hip_runtime.h>
#include <math.h>

#define DIMC 64
#define NE 512
#define NB 32
#define HWSZ 4096              // 64*64
#define NPTS (NB*HWSZ)         // 131072 points (B*H*W)
#define DECAYF 0.99f
#define OMD 0.01f
#define EPSF 1e-5f

// output offsets (floats) — out0 is [32,64,64,64] = 8388608 elements
#define O0 0
#define O1 8388608                 // diff scalar
#define O2 8388609                 // embed_ind [32,64,64]
#define O3 8519681                 // new_cluster_size [512]
#define O4 8520193                 // new_dictionary_avg [64,512]
#define O5 8552961                 // new_dictionary [64,512]
#define O6 8585729                 // mean_D scalar

// ws float layout
#define WS_DIFF   0
#define WS_COUNTS 64               // 512 floats
#define WS_ESUM   (64+512)         // [j][c] 512*64
#define WS_DT     (64+512+32768)   // [j][c] 512*64 transposed dict
#define WS_NORM   (64+512+32768+32768) // 512
#define WS_ZERO_FLOATS (64+512+32768)  // region to zero each launch

// -------- K1: transpose dictionary to [j][c] + per-code squared norms --------
__global__ void k_prep(const float* __restrict__ dict, float* __restrict__ ws) {
    int j = blockIdx.x, c = threadIdx.x;
    float v = dict[c * NE + j];
    ws[WS_DT + j * DIMC + c] = v;
    float s = v * v;
    #pragma unroll
    for (int off = 32; off > 0; off >>= 1) s += __shfl_down(s, off);
    if (c == 0) ws[WS_NORM + j] = s;
}

// -------- K2: assignment + quantize write + partial stats --------
__global__ __launch_bounds__(512, 2) void k_assign(
        const float* __restrict__ x, float* __restrict__ ws,
        float* __restrict__ out) {
    extern __shared__ float lds[];
    float* ldict = lds;                 // 32768 floats: [j][c]
    float* lnorm = lds + 32768;         // 512
    int*   lhist = (int*)(lds + 33280); // 512 ints
    float* lred  = lds + 33792;         // 8 floats

    const int tid = threadIdx.x;

    // stage dict rows (coalesced, conflict-free linear copy)
    const float4* dsrc = (const float4*)(ws + WS_DT);
    float4* ddst = (float4*)ldict;
    #pragma unroll
    for (int k = 0; k < 16; ++k) ddst[tid + 512 * k] = dsrc[tid + 512 * k];
    lnorm[tid] = ws[WS_NORM + tid];
    lhist[tid] = 0;
    __syncthreads();

    const int n = blockIdx.x * 512 + tid;
    const int b = n >> 12, hw = n & 4095;
    const float* xp = x + (size_t)b * (DIMC * HWSZ) + hw;
    float f[DIMC];
    #pragma unroll
    for (int c = 0; c < DIMC; ++c) f[c] = xp[c * HWSZ];

    float best = -3.4e38f;
    int bidx = 0;
    for (int j = 0; j < NE; ++j) {
        const float4* row = (const float4*)(ldict + j * DIMC);
        float s0 = 0.f, s1 = 0.f, s2 = 0.f, s3 = 0.f;
        #pragma unroll
        for (int c4 = 0; c4 < 16; ++c4) {
            float4 r = row[c4];
            const int cb = 4 * c4;
            s0 = fmaf(r.x, f[cb + 0], s0);
            s1 = fmaf(r.y, f[cb + 1], s1);
            s2 = fmaf(r.z, f[cb + 2], s2);
            s3 = fmaf(r.w, f[cb + 3], s3);
        }
        float s = (s0 + s1) + (s2 + s3);
        float score = 2.0f * s - lnorm[j];   // == -(dist) + ||f||^2 ; same argmax
        if (score > best) { best = score; bidx = j; }
    }

    atomicAdd(&lhist[bidx], 1);
    out[O2 + n] = (float)bidx;

    // quantize gather from LDS, NCHW write, diff partial
    float ssum = 0.f;
    float* o0 = out + O0 + (size_t)b * (DIMC * HWSZ) + hw;
    const float4* q4 = (const float4*)(ldict + bidx * DIMC);
    #pragma unroll
    for (int c4 = 0; c4 < 16; ++c4) {
        float4 q = q4[c4];
        const int cb = 4 * c4;
        o0[(cb + 0) * HWSZ] = q.x;
        o0[(cb + 1) * HWSZ] = q.y;
        o0[(cb + 2) * HWSZ] = q.z;
        o0[(cb + 3) * HWSZ] = q.w;
        float d0 = q.x - f[cb + 0]; ssum = fmaf(d0, d0, ssum);
        float d1 = q.y - f[cb + 1]; ssum = fmaf(d1, d1, ssum);
        float d2 = q.z - f[cb + 2]; ssum = fmaf(d2, d2, ssum);
        float d3 = q.w - f[cb + 3]; ssum = fmaf(d3, d3, ssum);
    }

    // embed_sum scatter (rounding-tolerant)
    float* es = ws + WS_ESUM + (size_t)bidx * DIMC;
    #pragma unroll
    for (int c = 0; c < DIMC; ++c) atomicAdd(&es[c], f[c]);

    // diff block reduction
    #pragma unroll
    for (int off = 32; off > 0; off >>= 1) ssum += __shfl_down(ssum, off);
    if ((tid & 63) == 0) lred[tid >> 6] = ssum;
    __syncthreads();
    if (tid == 0) {
        float t = 0.f;
        #pragma unroll
        for (int w = 0; w < 8; ++w) t += lred[w];
        atomicAdd(ws + WS_DIFF, t);
    }
    // counts flush (all lhist atomics happened before the __syncthreads above)
    atomicAdd(ws + WS_COUNTS + tid, (float)lhist[tid]);
}

// -------- K3: finalize EMA buffers / outputs --------
__global__ void k_final(const float* __restrict__ ws,
                        const float* __restrict__ cluster_size,
                        const float* __restrict__ davg,
                        float* __restrict__ out) {
    __shared__ float red[16];
    __shared__ float nsh;
    const int j = threadIdx.x;

    float cnt = ws[WS_COUNTS + j];
    float ncs = DECAYF * cluster_size[j] + OMD * cnt;
    out[O3 + j] = ncs;

    float v = ncs;
    #pragma unroll
    for (int off = 32; off > 0; off >>= 1) v += __shfl_down(v, off);
    if ((j & 63) == 0) red[j >> 6] = v;
    __syncthreads();
    if (j == 0) {
        float t = 0.f;
        #pragma unroll
        for (int w = 0; w < 8; ++w) t += red[w];
        nsh = t;
    }
    __syncthreads();
    const float n = nsh;
    const float csj = (ncs + EPSF) / (n + NE * EPSF) * n;

    float asum = 0.f;
    #pragma unroll
    for (int c = 0; c < DIMC; ++c) {
        float es = ws[WS_ESUM + (size_t)j * DIMC + c];
        float da = davg[c * NE + j];
        float nda = DECAYF * da + OMD * es;
        out[O4 + c * NE + j] = nda;
        float nd = nda / csj;
        out[O5 + c * NE + j] = nd;
        asum += fabsf(nd);
    }

    __syncthreads();   // red[] reuse barrier
    #pragma unroll
    for (int off = 32; off > 0; off >>= 1) asum += __shfl_down(asum, off);
    if ((j & 63) == 0) red[j >> 6] = asum;
    __syncthreads();
    if (j == 0) {
        float t = 0.f;
        #pragma unroll
        for (int w = 0; w < 8; ++w) t += red[w];
        out[O6] = t / 32768.0f;
        out[O1] = ws[WS_DIFF] / 8388608.0f;
    }
}

extern "C" void kernel_launch(void* const* d_in, const int* in_sizes, int n_in,
                              void* d_out, int out_size, void* d_ws, size_t ws_size,
                              hipStream_t stream) {
    const float* x    = (const float*)d_in[0];
    const float* dict = (const float*)d_in[1];
    const float* csz  = (const float*)d_in[2];
    const float* davg = (const float*)d_in[3];
    float* out = (float*)d_out;
    float* ws  = (float*)d_ws;

    // zero accumulator region (diff, counts, esum)
    hipMemsetAsync(ws, 0, (size_t)WS_ZERO_FLOATS * sizeof(float), stream);

    k_prep<<<512, 64, 0, stream>>>(dict, ws);

    const int lds_bytes = 33800 * 4;  // ldict + lnorm + lhist + lred
    hipFuncSetAttribute((const void*)k_assign,
                        hipFuncAttributeMaxDynamicSharedMemorySize, lds_bytes);
    k_assign<<<256, 512, lds_bytes, stream>>>(x, ws, out);

    k_final<<<1, 512, 0, stream>>>(ws, csz, davg, out);
}

// Round 3
// 245.688 us; speedup vs baseline: 12.0179x; 12.0179x over previous
//
#include <hip/hip_runtime.h>
#include <math.h>

#define DIMC 64
#define NE 512
#define HWSZ 4096              // 64*64
#define NPTS 131072            // B*H*W
#define DECAYF 0.99f
#define OMD 0.01f
#define EPSF 1e-5f

// output offsets (floats) — out0 is [32,64,64,64] = 8388608 elements
#define O0 0
#define O1 8388608                 // diff scalar
#define O2 8388609                 // embed_ind [32,64,64]
#define O3 8519681                 // new_cluster_size [512]
#define O4 8520193                 // new_dictionary_avg [64,512]
#define O5 8552961                 // new_dictionary [64,512]
#define O6 8585729                 // mean_D scalar

// ws float layout
#define WS_DIFF   0
#define WS_ESUM   64                       // [c][j] 64*512 (reduced)
#define WS_COUNTS (64+32768)               // 512 (reduced)
#define WS_DT     (64+32768+512)           // [j][c] transposed dict, 32768
#define WS_NORM   (WS_DT+32768)            // 512
#define WS_PART   (WS_NORM+512)            // 256 x 33280 partials
#define PART_STRIDE 33280                  // 32768 esum + 512 counts
#define NBLK 256
#define WS_NEED_BYTES ((size_t)(WS_PART + (size_t)NBLK * PART_STRIDE) * 4)

// -------- K1: transpose dictionary to [j][c] + per-code squared norms --------
__global__ void k_prep(const float* __restrict__ dict, float* __restrict__ ws) {
    int j = blockIdx.x, c = threadIdx.x;
    float v = dict[c * NE + j];
    ws[WS_DT + j * DIMC + c] = v;
    float s = v * v;
    #pragma unroll
    for (int off = 32; off > 0; off >>= 1) s += __shfl_down(s, off);
    if (c == 0) ws[WS_NORM + j] = s;
}

// -------- K2: assignment + quantize + per-block partial stats --------
// 256 blocks x 256 threads, 2 points per thread.
__global__ __launch_bounds__(256, 1) void k_assign(
        const float* __restrict__ x, float* __restrict__ ws,
        float* __restrict__ out, int use_part) {
    extern __shared__ float lds[];
    float* ldict = lds;                 // 32768 f: [j][c]; reused as esum_t [c][j]
    float* lnorm = lds + 32768;         // 512
    int*   lhist = (int*)(lds + 33280); // 512
    float* lred  = lds + 33792;         // 4

    const int tid = threadIdx.x;

    // stage dict (coalesced linear copy)
    {
        const float4* dsrc = (const float4*)(ws + WS_DT);
        float4* ddst = (float4*)ldict;
        #pragma unroll
        for (int k = 0; k < 32; ++k) ddst[tid + 256 * k] = dsrc[tid + 256 * k];
        lnorm[tid] = ws[WS_NORM + tid];
        lnorm[256 + tid] = ws[WS_NORM + 256 + tid];
        lhist[tid] = 0; lhist[256 + tid] = 0;
    }
    __syncthreads();

    const int n0 = blockIdx.x * 512 + tid;      // second point: n0 + 256
    const int b = n0 >> 12, hw0 = n0 & 4095;
    const float* xp = x + (size_t)b * (DIMC * HWSZ) + hw0;
    float f0[DIMC], f1[DIMC];
    #pragma unroll
    for (int c = 0; c < DIMC; ++c) { f0[c] = xp[c * HWSZ]; f1[c] = xp[c * HWSZ + 256]; }

    float best0 = -3.4e38f, best1 = -3.4e38f;
    int bi0 = 0, bi1 = 0;
    for (int j = 0; j < NE; ++j) {
        const float4* row = (const float4*)(ldict + j * DIMC);
        float a0 = 0.f, a1 = 0.f, a2 = 0.f, a3 = 0.f;
        float c0 = 0.f, c1 = 0.f, c2 = 0.f, c3 = 0.f;
        #pragma unroll
        for (int c4 = 0; c4 < 16; ++c4) {
            float4 r = row[c4];
            const int cb = 4 * c4;
            a0 = fmaf(r.x, f0[cb + 0], a0);
            a1 = fmaf(r.y, f0[cb + 1], a1);
            a2 = fmaf(r.z, f0[cb + 2], a2);
            a3 = fmaf(r.w, f0[cb + 3], a3);
            c0 = fmaf(r.x, f1[cb + 0], c0);
            c1 = fmaf(r.y, f1[cb + 1], c1);
            c2 = fmaf(r.z, f1[cb + 2], c2);
            c3 = fmaf(r.w, f1[cb + 3], c3);
        }
        float s0 = (a0 + a1) + (a2 + a3);
        float s1 = (c0 + c1) + (c2 + c3);
        float nrm = lnorm[j];
        float sc0 = 2.0f * s0 - nrm;
        float sc1 = 2.0f * s1 - nrm;
        if (sc0 > best0) { best0 = sc0; bi0 = j; }
        if (sc1 > best1) { best1 = sc1; bi1 = j; }
    }

    atomicAdd(&lhist[bi0], 1);
    atomicAdd(&lhist[bi1], 1);
    out[O2 + n0] = (float)bi0;
    out[O2 + n0 + 256] = (float)bi1;

    // quantize gather (ldict still dict) + NCHW write + diff partials
    float ssum = 0.f;
    float* o0 = out + O0 + (size_t)b * (DIMC * HWSZ) + hw0;
    const float4* q40 = (const float4*)(ldict + bi0 * DIMC);
    const float4* q41 = (const float4*)(ldict + bi1 * DIMC);
    #pragma unroll
    for (int c4 = 0; c4 < 16; ++c4) {
        float4 qa = q40[c4];
        float4 qb = q41[c4];
        const int cb = 4 * c4;
        o0[(cb + 0) * HWSZ] = qa.x;       o0[(cb + 0) * HWSZ + 256] = qb.x;
        o0[(cb + 1) * HWSZ] = qa.y;       o0[(cb + 1) * HWSZ + 256] = qb.y;
        o0[(cb + 2) * HWSZ] = qa.z;       o0[(cb + 2) * HWSZ + 256] = qb.z;
        o0[(cb + 3) * HWSZ] = qa.w;       o0[(cb + 3) * HWSZ + 256] = qb.w;
        float d;
        d = qa.x - f0[cb + 0]; ssum = fmaf(d, d, ssum);
        d = qa.y - f0[cb + 1]; ssum = fmaf(d, d, ssum);
        d = qa.z - f0[cb + 2]; ssum = fmaf(d, d, ssum);
        d = qa.w - f0[cb + 3]; ssum = fmaf(d, d, ssum);
        d = qb.x - f1[cb + 0]; ssum = fmaf(d, d, ssum);
        d = qb.y - f1[cb + 1]; ssum = fmaf(d, d, ssum);
        d = qb.z - f1[cb + 2]; ssum = fmaf(d, d, ssum);
        d = qb.w - f1[cb + 3]; ssum = fmaf(d, d, ssum);
    }

    __syncthreads();   // everyone done reading ldict
    // reuse ldict as esum_t[c][j] (64 x 512) — zero it
    {
        float4* e4 = (float4*)ldict;
        float4 z = {0.f, 0.f, 0.f, 0.f};
        #pragma unroll
        for (int k = 0; k < 32; ++k) e4[tid + 256 * k] = z;
    }
    __syncthreads();
    // scatter: banks spread by bidx (esum_t[c*512 + j], bank = j & 31)
    float* esum = ldict;
    #pragma unroll
    for (int c = 0; c < DIMC; ++c) {
        atomicAdd(&esum[c * NE + bi0], f0[c]);
        atomicAdd(&esum[c * NE + bi1], f1[c]);
    }
    __syncthreads();

    if (use_part) {
        float* part = ws + WS_PART + (size_t)blockIdx.x * PART_STRIDE;
        float4* p4 = (float4*)part;
        const float4* e4 = (const float4*)esum;
        #pragma unroll
        for (int k = 0; k < 32; ++k) p4[tid + 256 * k] = e4[tid + 256 * k];
        part[32768 + tid] = (float)lhist[tid];
        part[32768 + 256 + tid] = (float)lhist[256 + tid];
    } else {
        #pragma unroll
        for (int k = 0; k < 128; ++k)
            atomicAdd(&ws[WS_ESUM + tid + 256 * k], esum[tid + 256 * k]);
        atomicAdd(&ws[WS_COUNTS + tid], (float)lhist[tid]);
        atomicAdd(&ws[WS_COUNTS + 256 + tid], (float)lhist[256 + tid]);
    }

    // diff reduction (4 waves)
    #pragma unroll
    for (int off = 32; off > 0; off >>= 1) ssum += __shfl_down(ssum, off);
    if ((tid & 63) == 0) lred[tid >> 6] = ssum;
    __syncthreads();
    if (tid == 0) {
        float t = (lred[0] + lred[1]) + (lred[2] + lred[3]);
        atomicAdd(ws + WS_DIFF, t);
    }
}

// -------- K2b: tree-reduce per-block partials into WS_ESUM/WS_COUNTS --------
// 65 blocks x 128 threads = 8320 float4 positions (33280 floats)
__global__ void k_reduce(float* __restrict__ ws) {
    const int gid = blockIdx.x * 128 + threadIdx.x;   // [0, 8320)
    const float4* src = (const float4*)(ws + WS_PART);
    float4 acc = {0.f, 0.f, 0.f, 0.f};
    #pragma unroll 4
    for (int p = 0; p < NBLK; ++p) {
        float4 v = src[(size_t)p * (PART_STRIDE / 4) + gid];
        acc.x += v.x; acc.y += v.y; acc.z += v.z; acc.w += v.w;
    }
    ((float4*)(ws + WS_ESUM))[gid] = acc;   // COUNTS region follows ESUM contiguously
}

// -------- K3: finalize EMA buffers / outputs --------
__global__ void k_final(const float* __restrict__ ws,
                        const float* __restrict__ cluster_size,
                        const float* __restrict__ davg,
                        float* __restrict__ out) {
    __shared__ float red[16];
    __shared__ float nsh;
    const int j = threadIdx.x;

    float cnt = ws[WS_COUNTS + j];
    float ncs = DECAYF * cluster_size[j] + OMD * cnt;
    out[O3 + j] = ncs;

    float v = ncs;
    #pragma unroll
    for (int off = 32; off > 0; off >>= 1) v += __shfl_down(v, off);
    if ((j & 63) == 0) red[j >> 6] = v;
    __syncthreads();
    if (j == 0) {
        float t = 0.f;
        #pragma unroll
        for (int w = 0; w < 8; ++w) t += red[w];
        nsh = t;
    }
    __syncthreads();
    const float n = nsh;
    const float csj = (ncs + EPSF) / (n + NE * EPSF) * n;

    float asum = 0.f;
    #pragma unroll
    for (int c = 0; c < DIMC; ++c) {
        float es = ws[WS_ESUM + c * NE + j];
        float da = davg[c * NE + j];
        float nda = DECAYF * da + OMD * es;
        out[O4 + c * NE + j] = nda;
        float nd = nda / csj;
        out[O5 + c * NE + j] = nd;
        asum += fabsf(nd);
    }

    __syncthreads();
    #pragma unroll
    for (int off = 32; off > 0; off >>= 1) asum += __shfl_down(asum, off);
    if ((j & 63) == 0) red[j >> 6] = asum;
    __syncthreads();
    if (j == 0) {
        float t = 0.f;
        #pragma unroll
        for (int w = 0; w < 8; ++w) t += red[w];
        out[O6] = t / 32768.0f;
        out[O1] = ws[WS_DIFF] / 8388608.0f;
    }
}

extern "C" void kernel_launch(void* const* d_in, const int* in_sizes, int n_in,
                              void* d_out, int out_size, void* d_ws, size_t ws_size,
                              hipStream_t stream) {
    const float* x    = (const float*)d_in[0];
    const float* dict = (const float*)d_in[1];
    const float* csz  = (const float*)d_in[2];
    const float* davg = (const float*)d_in[3];
    float* out = (float*)d_out;
    float* ws  = (float*)d_ws;

    const int use_part = (ws_size >= WS_NEED_BYTES) ? 1 : 0;

    // zero diff + esum + counts (esum/counts only needed for atomic fallback,
    // but cheap either way; k_reduce fully overwrites them when use_part)
    hipMemsetAsync(ws, 0, (size_t)(WS_ESUM + 32768 + 512) * sizeof(float), stream);

    k_prep<<<512, 64, 0, stream>>>(dict, ws);

    const int lds_bytes = 33800 * 4;
    hipFuncSetAttribute((const void*)k_assign,
                        hipFuncAttributeMaxDynamicSharedMemorySize, lds_bytes);
    k_assign<<<NBLK, 256, lds_bytes, stream>>>(x, ws, out, use_part);

    if (use_part) k_reduce<<<65, 128, 0, stream>>>(ws);

    k_final<<<1, 512, 0, stream>>>(ws, csz, davg, out);
}